// Round 10
// baseline (122.264 us; speedup 1.0000x reference)
//
#include <hip/hip_runtime.h>

#define NQ 2048
#define NO 2048
#define NOC 64   // o-chunks of 32

// ws layout (float offsets): Ph [NOC][NQ][64] (pre-Wv h partials, 34 MB),
// Ps [NOC][NQ]. ws_size ~256 MiB (R6 fill evidence).
constexpr size_t OFF_PH = 0;
constexpr size_t OFF_PS = (size_t)NOC * NQ * 64;

// ---------------------------------------------------------------------------
// Main: 2048 blocks = 32 q-groups(64) x 64 o-chunks(32). lane = q.
// No u-tile (R7) and no big register arrays (R5/R8 AGPR trap): u recomputed
// per l from a packed LDS coeff row wtab[l] = {A,B,C,b1,W2,D,E,F} (+3 fma/l),
// t-tile computed in-block. LDS = 19.4 KB -> 8 blocks/CU by LDS; (256,6)
// VGPR cap 85 -> 6 blocks/CU resident (24 waves/CU vs R7's ~11; R8 showed
// occupancy 35% was the stall, not the LDS pipe).
// Phase A: wave w -> o-slice [8w,+8); l-outer, lg[8] in VGPRs.
// Phase B: wave w -> l-slice [16w,+16), all 32 o; raw h_obs rows (Wv applied
// post-normalize in comb). Two barriers; no atomics; disjoint outputs.
// ---------------------------------------------------------------------------
__global__ __launch_bounds__(256, 6) void gano_main(
    const float* __restrict__ h_obs,
    const float* __restrict__ pos_obs,
    const float* __restrict__ pos_query,
    const float* __restrict__ W1,
    const float* __restrict__ b1,
    const float* __restrict__ W2,
    float* __restrict__ Ph,
    float* __restrict__ Ps)
{
    __shared__ __align__(16) float wtab[64 * 8];  // [l]{A,B,C,b1,W2,D,E,F}
    __shared__ __align__(16) float tl[64 * 32];   // t [l][o_local]
    __shared__ float po[3 * 32];                  // pos_o [c][o_local]
    __shared__ float ue[32 * 64];                 // e [o][q-lane]
    __shared__ float sbuf[4 * 64];

    const int tid  = threadIdx.x;
    const int lane = tid & 63;
    const int wave = __builtin_amdgcn_readfirstlane(tid >> 6);
    const int qg = blockIdx.x >> 6;   // 0..31
    const int oc = blockIdx.x & 63;   // 0..63
    const int obase = oc * 32;
    const int q  = qg * 64 + lane;

    // ---- stage coeff table (first 64 threads; l = tid; coalesced) ----
    if (tid < 64) {
        float w0 = W1[0*64+tid], w1_ = W1[1*64+tid], w2_ = W1[2*64+tid];
        float w3 = W1[3*64+tid], w4  = W1[4*64+tid], w5  = W1[5*64+tid];
        float w6 = W1[6*64+tid], w7  = W1[7*64+tid], w8  = W1[8*64+tid];
        float* r = wtab + tid * 8;
        r[0] = w0 + w6;  r[1] = w1_ + w7;  r[2] = w2_ + w8;   // A,B,C (u coeffs)
        r[3] = b1[tid];  r[4] = W2[tid];
        r[5] = w3 - w6;  r[6] = w4 - w7;   r[7] = w5 - w8;    // D,E,F (t coeffs)
    }
    if (tid < 32) {   // pos_o for this chunk
        po[tid]      = pos_obs[(obase + tid) * 3 + 0];
        po[32 + tid] = pos_obs[(obase + tid) * 3 + 1];
        po[64 + tid] = pos_obs[(obase + tid) * 3 + 2];
    }
    float pq0 = pos_query[q * 3 + 0];
    float pq1 = pos_query[q * 3 + 1];
    float pq2 = pos_query[q * 3 + 2];
    __syncthreads();   // sync0: wtab/po visible (t-compute reads both)

    // ---- t-tile: o = lane&31, half = lane>>5; wave w covers l in [16w,+16) ----
    {
        const int o = lane & 31, half = lane >> 5;
        float p0 = po[o], p1 = po[32 + o], p2 = po[64 + o];
#pragma unroll
        for (int j = 0; j < 8; ++j) {
            int l = wave * 16 + j * 2 + half;
            const float* r = wtab + l * 8;
            tl[l * 32 + o] = p0 * r[5] + p1 * r[6] + p2 * r[7];  // 2-way bank = free
        }
    }
    __syncthreads();   // sync1: t-tile ready

    // ---- Phase A: wave w -> o-slice [8w,+8); l-outer, u recomputed per l ----
    float lg[8];
#pragma unroll
    for (int o = 0; o < 8; ++o) lg[o] = 0.f;
    const int ow = wave * 8;
#pragma unroll 16
    for (int l = 0; l < 64; ++l) {
        float4 c4 = *(const float4*)(wtab + l * 8);      // broadcast b128: A,B,C,b1
        float wl  = wtab[l * 8 + 4];                     // broadcast b32: W2[l]
        float u   = fmaf(pq2, c4.z, fmaf(pq1, c4.y, fmaf(pq0, c4.x, c4.w)));
        float4 ta = *(const float4*)(tl + l * 32 + ow);      // broadcast b128: o 0..3
        float4 tb = *(const float4*)(tl + l * 32 + ow + 4);  // broadcast b128: o 4..7
        lg[0] += wl * fmaxf(u + ta.x, 0.f);
        lg[1] += wl * fmaxf(u + ta.y, 0.f);
        lg[2] += wl * fmaxf(u + ta.z, 0.f);
        lg[3] += wl * fmaxf(u + ta.w, 0.f);
        lg[4] += wl * fmaxf(u + tb.x, 0.f);
        lg[5] += wl * fmaxf(u + tb.y, 0.f);
        lg[6] += wl * fmaxf(u + tb.z, 0.f);
        lg[7] += wl * fmaxf(u + tb.w, 0.f);
    }
    // ---- mask + exp; e -> LDS ----
    float spart = 0.f;
#pragma unroll
    for (int o = 0; o < 8; ++o) {
        float d0 = pq0 - po[ow + o];                     // broadcast b32
        float d1 = pq1 - po[32 + ow + o];
        float d2 = pq2 - po[64 + ow + o];
        float dd = d0 * d0 + d1 * d1 + d2 * d2;
        float ev = (dd > 0.25f) ? 0.f : __expf(lg[o]);   // logits O(1): raw exp safe
        spart += ev;
        ue[(ow + o) * 64 + lane] = ev;                   // 2-way bank = free
    }
    sbuf[wave * 64 + lane] = spart;
    __syncthreads();   // sync2: e-buffer ready

    // ---- Phase B: wave w -> l-slice [16w,+16), all 32 o, raw h_obs rows ----
    const int lw = wave * 16;
    float h0 = 0.f, h1 = 0.f, h2 = 0.f, h3 = 0.f, h4 = 0.f, h5 = 0.f, h6 = 0.f, h7 = 0.f;
    float h8 = 0.f, h9 = 0.f, hA = 0.f, hB = 0.f, hC = 0.f, hD = 0.f, hE = 0.f, hF = 0.f;
#pragma unroll 4
    for (int o = 0; o < 32; ++o) {
        float eo = ue[o * 64 + lane];                    // b32, 2-way = free
        const float4* hr = (const float4*)(h_obs + (size_t)(obase + o) * 64 + lw);  // uniform, L1/L2-hot
        float4 v0 = hr[0], v1 = hr[1], v2 = hr[2], v3 = hr[3];
        h0 += eo * v0.x; h1 += eo * v0.y; h2 += eo * v0.z; h3 += eo * v0.w;
        h4 += eo * v1.x; h5 += eo * v1.y; h6 += eo * v1.z; h7 += eo * v1.w;
        h8 += eo * v2.x; h9 += eo * v2.y; hA += eo * v2.z; hB += eo * v2.w;
        hC += eo * v3.x; hD += eo * v3.y; hE += eo * v3.z; hF += eo * v3.w;
    }

    // ---- stores: disjoint per wave, float4 ----
    float* hp = Ph + ((size_t)oc * NQ + (size_t)qg * 64 + lane) * 64 + lw;
    ((float4*)hp)[0] = make_float4(h0, h1, h2, h3);
    ((float4*)hp)[1] = make_float4(h4, h5, h6, h7);
    ((float4*)hp)[2] = make_float4(h8, h9, hA, hB);
    ((float4*)hp)[3] = make_float4(hC, hD, hE, hF);
    if (wave == 0) {
        float s = sbuf[lane] + sbuf[64 + lane] + sbuf[128 + lane] + sbuf[192 + lane];
        Ps[(size_t)oc * NQ + (size_t)qg * 64 + lane] = s;
    }
}

// ---------------------------------------------------------------------------
// Combine + Wv projection: g[q][k] = sum_c Ph[c][q][k]; s = sum_c Ps[c][q];
// out[q][l] = (g[q][:]/s) @ Wv + bv.  512 blocks; block = 4 q; wave w owns
// query w; Wv staged in LDS (lane-consecutive b32, conflict-free).
// ---------------------------------------------------------------------------
__global__ __launch_bounds__(256, 2) void gano_comb(
    const float* __restrict__ Ph,
    const float* __restrict__ Ps,
    const float* __restrict__ Wv,
    const float* __restrict__ bv,
    float* __restrict__ out)
{
    __shared__ __align__(16) float wv[64 * 64];
    __shared__ __align__(16) float g[4 * 68];
    const int tid  = threadIdx.x;
    const int lane = tid & 63;
    const int wave = tid >> 6;
    const int q0 = blockIdx.x * 4;
    {
        const float4* src = (const float4*)Wv;
        float4* dst = (float4*)wv;
#pragma unroll
        for (int k = 0; k < 4; ++k) dst[tid + k * 256] = src[tid + k * 256];
    }
    {
        const int qi = wave, k = lane;
        float acc = 0.f;
#pragma unroll 8
        for (int c = 0; c < NOC; ++c)
            acc += Ph[((size_t)c * NQ + q0 + qi) * 64 + k];
        g[qi * 68 + k] = acc;
        if (k == 0) {
            float ss = 0.f;
#pragma unroll 8
            for (int c = 0; c < NOC; ++c) ss += Ps[(size_t)c * NQ + q0 + qi];
            g[qi * 68 + 64] = ss;
        }
    }
    __syncthreads();
    const float* gq = g + wave * 68;            // wave-uniform broadcast
    float inv = 1.0f / gq[64];
    float a0 = 0.f, a1 = 0.f, a2 = 0.f, a3 = 0.f;
#pragma unroll
    for (int kb = 0; kb < 16; ++kb) {
        float4 g4 = *(const float4*)(gq + kb * 4);
        a0 += g4.x * wv[(kb * 4 + 0) * 64 + lane];
        a1 += g4.y * wv[(kb * 4 + 1) * 64 + lane];
        a2 += g4.z * wv[(kb * 4 + 2) * 64 + lane];
        a3 += g4.w * wv[(kb * 4 + 3) * 64 + lane];
    }
    out[(size_t)(q0 + wave) * 64 + lane] = ((a0 + a1) + (a2 + a3)) * inv + bv[lane];
}

// ---------------------------------------------------------------------------
extern "C" void kernel_launch(void* const* d_in, const int* in_sizes, int n_in,
                              void* d_out, int out_size, void* d_ws, size_t ws_size,
                              hipStream_t stream) {
    const float* h_obs     = (const float*)d_in[0];
    // d_in[1] = x_obs (unused by reference)
    const float* pos_obs   = (const float*)d_in[2];
    const float* pos_query = (const float*)d_in[3];
    const float* W1        = (const float*)d_in[4];
    const float* b1        = (const float*)d_in[5];
    const float* W2        = (const float*)d_in[6];
    // d_in[7] = b2: constant shift, cancels in softmax
    const float* Wv        = (const float*)d_in[8];
    const float* bv        = (const float*)d_in[9];
    float* ws  = (float*)d_ws;
    float* out = (float*)d_out;

    gano_main<<<dim3(2048), dim3(256), 0, stream>>>(h_obs, pos_obs, pos_query,
                                                    W1, b1, W2, ws + OFF_PH, ws + OFF_PS);
    gano_comb<<<dim3(NQ / 4), dim3(256), 0, stream>>>(ws + OFF_PH, ws + OFF_PS, Wv, bv, out);
}

// Round 11
// 116.330 us; speedup vs baseline: 1.0510x; 1.0510x over previous
//
#include <hip/hip_runtime.h>

#define NQ 2048
#define NO 2048
#define NOC 32   // o-chunks of 64 (two 32-o sub-chunks per block)

// ws layout (float offsets): Ph [NOC][NQ][64] (pre-Wv h partials, 17 MB),
// Ps [NOC][NQ]. R10 lesson: partial traffic costs double (our HBM write +
// slowdown of the harness's 268MB poison fill it overlaps with) — keep 17MB.
constexpr size_t OFF_PH = 0;
constexpr size_t OFF_PS = (size_t)NOC * NQ * 64;

// ---------------------------------------------------------------------------
// Main: 1024 blocks = 32 q-groups(64) x 32 o-chunks(64). lane = q.
// R10 inner machinery (no AGPR-trap arrays, 20KB LDS, 6 blocks/CU) + R7
// footprint (NOC=32). Each block loops st=0,1 over 32-o sub-chunks:
//   u recomputed per l from wtab[l]={A,B,C,b1,W2,D,E,F} (+3 fma/l/wave)
//   t-tile [l][32 o] computed in-block; phase A: wave w -> 8-o slice, lg[8];
//   phase B: wave w -> 16-l slice over 32 o's, h persists across sub-chunks.
// Barrier A (per st) doubles as t-ready + prior-ue-read guard; barrier B = e
// ready. No atomics; disjoint outputs.
// ---------------------------------------------------------------------------
__global__ __launch_bounds__(256, 6) void gano_main(
    const float* __restrict__ h_obs,
    const float* __restrict__ pos_obs,
    const float* __restrict__ pos_query,
    const float* __restrict__ W1,
    const float* __restrict__ b1,
    const float* __restrict__ W2,
    float* __restrict__ Ph,
    float* __restrict__ Ps)
{
    __shared__ __align__(16) float wtab[64 * 8];  // [l]{A,B,C,b1,W2,D,E,F}
    __shared__ __align__(16) float tl[64 * 32];   // t [l][o_local(32)]
    __shared__ float po[3 * 32];                  // pos_o [c][o_local]
    __shared__ float ue[32 * 64];                 // e [o_local][q-lane]
    __shared__ float sbuf[4 * 64];

    const int tid  = threadIdx.x;
    const int lane = tid & 63;
    const int wave = __builtin_amdgcn_readfirstlane(tid >> 6);
    const int qg = blockIdx.x >> 5;   // 0..31
    const int oc = blockIdx.x & 31;   // 0..31
    const int q  = qg * 64 + lane;
    const int ow = wave * 8;          // phase A o-slice base
    const int lw = wave * 16;         // phase B l-slice base

    // ---- stage coeff table (first 64 threads; l = tid) ----
    if (tid < 64) {
        float w0 = W1[0*64+tid], w1_ = W1[1*64+tid], w2_ = W1[2*64+tid];
        float w3 = W1[3*64+tid], w4  = W1[4*64+tid], w5  = W1[5*64+tid];
        float w6 = W1[6*64+tid], w7  = W1[7*64+tid], w8  = W1[8*64+tid];
        float* r = wtab + tid * 8;
        r[0] = w0 + w6;  r[1] = w1_ + w7;  r[2] = w2_ + w8;   // u coeffs
        r[3] = b1[tid];  r[4] = W2[tid];
        r[5] = w3 - w6;  r[6] = w4 - w7;   r[7] = w5 - w8;    // t coeffs
    }
    float pq0 = pos_query[q * 3 + 0];
    float pq1 = pos_query[q * 3 + 1];
    float pq2 = pos_query[q * 3 + 2];
    __syncthreads();   // sync0: wtab visible

    float h0 = 0.f, h1 = 0.f, h2 = 0.f, h3 = 0.f, h4 = 0.f, h5 = 0.f, h6 = 0.f, h7 = 0.f;
    float h8 = 0.f, h9 = 0.f, hA = 0.f, hB = 0.f, hC = 0.f, hD = 0.f, hE = 0.f, hF = 0.f;
    float spart = 0.f;

#pragma unroll
    for (int st = 0; st < 2; ++st) {
        const int ob = oc * 64 + st * 32;

        // ---- t-tile + po: o = lane&31, half = lane>>5 ----
        {
            const int o = lane & 31, half = lane >> 5;
            float p0 = pos_obs[(ob + o) * 3 + 0];
            float p1 = pos_obs[(ob + o) * 3 + 1];
            float p2 = pos_obs[(ob + o) * 3 + 2];
            if (wave == 0 && half == 0) { po[o] = p0; po[32 + o] = p1; po[64 + o] = p2; }
#pragma unroll
            for (int j = 0; j < 8; ++j) {
                int l = wave * 16 + j * 2 + half;
                const float* r = wtab + l * 8;
                tl[l * 32 + o] = p0 * r[5] + p1 * r[6] + p2 * r[7];  // 2-way bank = free
            }
        }
        __syncthreads();   // barrier A: t/po ready; prior ue reads (st-1 phase B) done

        // ---- Phase A: wave w -> o-slice [ow,+8); l-outer, u recomputed ----
        float lg[8];
#pragma unroll
        for (int o = 0; o < 8; ++o) lg[o] = 0.f;
#pragma unroll 16
        for (int l = 0; l < 64; ++l) {
            float4 c4 = *(const float4*)(wtab + l * 8);       // broadcast: A,B,C,b1
            float wl  = wtab[l * 8 + 4];                      // broadcast: W2[l]
            float u   = fmaf(pq2, c4.z, fmaf(pq1, c4.y, fmaf(pq0, c4.x, c4.w)));
            float4 ta = *(const float4*)(tl + l * 32 + ow);       // o 0..3
            float4 tb = *(const float4*)(tl + l * 32 + ow + 4);   // o 4..7
            lg[0] += wl * fmaxf(u + ta.x, 0.f);
            lg[1] += wl * fmaxf(u + ta.y, 0.f);
            lg[2] += wl * fmaxf(u + ta.z, 0.f);
            lg[3] += wl * fmaxf(u + ta.w, 0.f);
            lg[4] += wl * fmaxf(u + tb.x, 0.f);
            lg[5] += wl * fmaxf(u + tb.y, 0.f);
            lg[6] += wl * fmaxf(u + tb.z, 0.f);
            lg[7] += wl * fmaxf(u + tb.w, 0.f);
        }
        // ---- mask + exp; e -> LDS ----
#pragma unroll
        for (int o = 0; o < 8; ++o) {
            float d0 = pq0 - po[ow + o];                      // broadcast
            float d1 = pq1 - po[32 + ow + o];
            float d2 = pq2 - po[64 + ow + o];
            float dd = d0 * d0 + d1 * d1 + d2 * d2;
            float ev = (dd > 0.25f) ? 0.f : __expf(lg[o]);    // logits O(1): raw exp safe
            spart += ev;
            ue[(ow + o) * 64 + lane] = ev;                    // 2-way bank = free
        }
        __syncthreads();   // barrier B: e-buffer ready

        // ---- Phase B: wave w -> l-slice [lw,+16), 32 o's, raw h_obs rows ----
#pragma unroll 4
        for (int o = 0; o < 32; ++o) {
            float eo = ue[o * 64 + lane];                     // b32, 2-way = free
            const float4* hr = (const float4*)(h_obs + (size_t)(ob + o) * 64 + lw); // uniform
            float4 v0 = hr[0], v1 = hr[1], v2 = hr[2], v3 = hr[3];
            h0 += eo * v0.x; h1 += eo * v0.y; h2 += eo * v0.z; h3 += eo * v0.w;
            h4 += eo * v1.x; h5 += eo * v1.y; h6 += eo * v1.z; h7 += eo * v1.w;
            h8 += eo * v2.x; h9 += eo * v2.y; hA += eo * v2.z; hB += eo * v2.w;
            hC += eo * v3.x; hD += eo * v3.y; hE += eo * v3.z; hF += eo * v3.w;
        }
    }

    // ---- stores: disjoint per wave, float4 ----
    float* hp = Ph + ((size_t)oc * NQ + (size_t)qg * 64 + lane) * 64 + lw;
    ((float4*)hp)[0] = make_float4(h0, h1, h2, h3);
    ((float4*)hp)[1] = make_float4(h4, h5, h6, h7);
    ((float4*)hp)[2] = make_float4(h8, h9, hA, hB);
    ((float4*)hp)[3] = make_float4(hC, hD, hE, hF);
    sbuf[wave * 64 + lane] = spart;
    __syncthreads();
    if (wave == 0) {
        float s = sbuf[lane] + sbuf[64 + lane] + sbuf[128 + lane] + sbuf[192 + lane];
        Ps[(size_t)oc * NQ + (size_t)qg * 64 + lane] = s;
    }
}

// ---------------------------------------------------------------------------
// Combine + Wv projection (R7-measured structure): g[q][k] = sum_c Ph[c][q][k];
// s = sum_c Ps[c][q]; out[q][l] = (g[q][:]/s) @ Wv + bv.  512 blocks.
// ---------------------------------------------------------------------------
__global__ __launch_bounds__(256, 2) void gano_comb(
    const float* __restrict__ Ph,
    const float* __restrict__ Ps,
    const float* __restrict__ Wv,
    const float* __restrict__ bv,
    float* __restrict__ out)
{
    __shared__ __align__(16) float wv[64 * 64];
    __shared__ __align__(16) float g[4 * 68];
    const int tid  = threadIdx.x;
    const int lane = tid & 63;
    const int wave = tid >> 6;
    const int q0 = blockIdx.x * 4;
    {
        const float4* src = (const float4*)Wv;
        float4* dst = (float4*)wv;
#pragma unroll
        for (int k = 0; k < 4; ++k) dst[tid + k * 256] = src[tid + k * 256];
    }
    {
        const int qi = wave, k = lane;
        float acc = 0.f;
#pragma unroll
        for (int c = 0; c < NOC; ++c)
            acc += Ph[((size_t)c * NQ + q0 + qi) * 64 + k];
        g[qi * 68 + k] = acc;
        if (k == 0) {
            float ss = 0.f;
#pragma unroll
            for (int c = 0; c < NOC; ++c) ss += Ps[(size_t)c * NQ + q0 + qi];
            g[qi * 68 + 64] = ss;
        }
    }
    __syncthreads();
    const float* gq = g + wave * 68;            // wave-uniform broadcast
    float inv = 1.0f / gq[64];
    float a0 = 0.f, a1 = 0.f, a2 = 0.f, a3 = 0.f;
#pragma unroll
    for (int kb = 0; kb < 16; ++kb) {
        float4 g4 = *(const float4*)(gq + kb * 4);
        a0 += g4.x * wv[(kb * 4 + 0) * 64 + lane];
        a1 += g4.y * wv[(kb * 4 + 1) * 64 + lane];
        a2 += g4.z * wv[(kb * 4 + 2) * 64 + lane];
        a3 += g4.w * wv[(kb * 4 + 3) * 64 + lane];
    }
    out[(size_t)(q0 + wave) * 64 + lane] = ((a0 + a1) + (a2 + a3)) * inv + bv[lane];
}

// ---------------------------------------------------------------------------
extern "C" void kernel_launch(void* const* d_in, const int* in_sizes, int n_in,
                              void* d_out, int out_size, void* d_ws, size_t ws_size,
                              hipStream_t stream) {
    const float* h_obs     = (const float*)d_in[0];
    // d_in[1] = x_obs (unused by reference)
    const float* pos_obs   = (const float*)d_in[2];
    const float* pos_query = (const float*)d_in[3];
    const float* W1        = (const float*)d_in[4];
    const float* b1        = (const float*)d_in[5];
    const float* W2        = (const float*)d_in[6];
    // d_in[7] = b2: constant shift, cancels in softmax
    const float* Wv        = (const float*)d_in[8];
    const float* bv        = (const float*)d_in[9];
    float* ws  = (float*)d_ws;
    float* out = (float*)d_out;

    gano_main<<<dim3(1024), dim3(256), 0, stream>>>(h_obs, pos_obs, pos_query,
                                                    W1, b1, W2, ws + OFF_PH, ws + OFF_PS);
    gano_comb<<<dim3(NQ / 4), dim3(256), 0, stream>>>(ws + OFF_PH, ws + OFF_PS, Wv, bv, out);
}